// Round 1
// baseline (1011.190 us; speedup 1.0000x reference)
//
#include <hip/hip_runtime.h>
#include <cstdint>

#define NP 4096   // points
#define DIMF 2048 // feature dim
#define NC 256    // classes
#define MAXIT 100

typedef __bf16 bf16x8 __attribute__((ext_vector_type(8)));
typedef float f32x4 __attribute__((ext_vector_type(4)));

__device__ inline unsigned short f2b(float f) {
  union { float f; unsigned u; } v; v.f = f;
  unsigned r = v.u + 0x7fffu + ((v.u >> 16) & 1u);  // RNE
  return (unsigned short)(r >> 16);
}
__device__ inline float b2f(unsigned short u) {
  union { unsigned u; float f; } v; v.u = ((unsigned)u) << 16;
  return v.f;
}

// ---------------- init (ws is poisoned 0xAA before every call) ----------------
__global__ __launch_bounds__(128) void initk(int* done, float* oldE, double* Ed,
                                             unsigned* ctr, float* sig) {
  int t = threadIdx.x;
  if (t < MAXIT) { Ed[t] = 0.0; ctr[t] = 0u; }
  if (t == 0) { *done = 0; *oldE = __int_as_float(0x7f800000); *sig = 0.0f; }
}

// ---------------- W f32 -> bf16 ----------------
__global__ __launch_bounds__(256) void castk(const float* __restrict__ W,
                                             unsigned short* __restrict__ Wb) {
  size_t i = ((size_t)blockIdx.x * 256 + threadIdx.x) * 4;
  float4 v = *(const float4*)&W[i];
  ushort4 o; o.x = f2b(v.x); o.y = f2b(v.y); o.z = f2b(v.z); o.w = f2b(v.w);
  *(ushort4*)&Wb[i] = o;
}

// ---------------- row-normalize x -> F(bf16), x -> xb(bf16), sqF = sum(F_bf16^2) ----
__global__ __launch_bounds__(256) void rownorm(const float* __restrict__ x,
                                               unsigned short* __restrict__ F,
                                               unsigned short* __restrict__ xb,
                                               float* __restrict__ sqF) {
  const int row = blockIdx.x, tid = threadIdx.x;
  const float* rp = x + (size_t)row * DIMF;
  float4 a = *(const float4*)&rp[tid * 8];
  float4 b = *(const float4*)&rp[tid * 8 + 4];
  float f[8] = {a.x, a.y, a.z, a.w, b.x, b.y, b.z, b.w};
  float s = 0.f;
#pragma unroll
  for (int k = 0; k < 8; k++) s += f[k] * f[k];
  __shared__ float red[256];
  red[tid] = s; __syncthreads();
  for (int st = 128; st >= 1; st >>= 1) {
    if (tid < st) red[tid] += red[tid + st];
    __syncthreads();
  }
  float inv = 1.0f / sqrtf(red[0]);
  __syncthreads();
  unsigned short fb[8], xbv[8];
  float s2 = 0.f;
#pragma unroll
  for (int k = 0; k < 8; k++) {
    fb[k] = f2b(f[k] * inv);
    xbv[k] = f2b(f[k]);
    float q = b2f(fb[k]);
    s2 += q * q;
  }
  *(ushort4*)&F[(size_t)row * DIMF + tid * 8]      = *(ushort4*)&fb[0];
  *(ushort4*)&F[(size_t)row * DIMF + tid * 8 + 4]  = *(ushort4*)&fb[4];
  *(ushort4*)&xb[(size_t)row * DIMF + tid * 8]     = *(ushort4*)&xbv[0];
  *(ushort4*)&xb[(size_t)row * DIMF + tid * 8 + 4] = *(ushort4*)&xbv[4];
  red[tid] = s2; __syncthreads();
  for (int st = 128; st >= 1; st >>= 1) {
    if (tid < st) red[tid] += red[tid + st];
    __syncthreads();
  }
  if (tid == 0) sqF[row] = red[0];
}

// ---------------- generic bf16 MFMA GEMM: C[M,N] = A[M,K] * B[N,K]^T (+epilogue) ----
// EPI 0: C = acc + aux[col]   (logits, aux = bias)
// EPI 1: C = max(aux[row]+aux[col]-2*acc, 0)   (d2, aux = sqF)
// EPI 2: C = acc              (pairwise P; early-exit on *done)
template <int BM, int BN, int WR, int WC, int EPI>
__global__ __launch_bounds__(256) void gemm_bt(const unsigned short* __restrict__ A,
                                               const unsigned short* __restrict__ B,
                                               float* __restrict__ C,
                                               int M, int N, int K,
                                               const float* __restrict__ aux,
                                               const int* __restrict__ done) {
  if (EPI == 2) { if (*done) return; }
  constexpr int WM = BM / WR, WN = BN / WC;
  constexpr int TM = WM / 16, TN = WN / 16;
  constexpr int LDT = 40;  // padded row stride (bf16 elems): 80B, 2-way-bank-free reads
  __shared__ __align__(16) unsigned short sA[BM * LDT];
  __shared__ __align__(16) unsigned short sB[BN * LDT];
  const int tid = threadIdx.x;
  const int wid = tid >> 6, lane = tid & 63;
  const int wr = wid / WC, wc = wid % WC;
  const int l15 = lane & 15, l16 = lane >> 4;
  const int bm = blockIdx.x * BM, bn = blockIdx.y * BN;
  f32x4 acc[TM][TN];
#pragma unroll
  for (int m = 0; m < TM; m++)
#pragma unroll
    for (int n = 0; n < TN; n++) acc[m][n] = 0.0f;

  for (int k0 = 0; k0 < K; k0 += 32) {
    for (int i = tid; i < BM * 4; i += 256) {
      int r = i >> 2, ch = i & 3;
      *(uint4*)&sA[r * LDT + ch * 8] =
          *(const uint4*)&A[(size_t)(bm + r) * K + k0 + ch * 8];
    }
    for (int i = tid; i < BN * 4; i += 256) {
      int r = i >> 2, ch = i & 3;
      *(uint4*)&sB[r * LDT + ch * 8] =
          *(const uint4*)&B[(size_t)(bn + r) * K + k0 + ch * 8];
    }
    __syncthreads();
    bf16x8 af[TM], bf[TN];
#pragma unroll
    for (int m = 0; m < TM; m++)
      af[m] = *(const bf16x8*)&sA[(wr * WM + m * 16 + l15) * LDT + l16 * 8];
#pragma unroll
    for (int n = 0; n < TN; n++)
      bf[n] = *(const bf16x8*)&sB[(wc * WN + n * 16 + l15) * LDT + l16 * 8];
#pragma unroll
    for (int m = 0; m < TM; m++)
#pragma unroll
      for (int n = 0; n < TN; n++)
        acc[m][n] = __builtin_amdgcn_mfma_f32_16x16x32_bf16(af[m], bf[n], acc[m][n], 0, 0, 0);
    __syncthreads();
  }
  // epilogue: D elem j -> row = ... + (lane>>4)*4 + j, col = ... + (lane&15)
#pragma unroll
  for (int m = 0; m < TM; m++) {
    int row0 = bm + wr * WM + m * 16 + l16 * 4;
#pragma unroll
    for (int n = 0; n < TN; n++) {
      int col = bn + wc * WN + n * 16 + l15;
#pragma unroll
      for (int j = 0; j < 4; j++) {
        int row = row0 + j;
        float v = acc[m][n][j];
        if (EPI == 0) {
          C[(size_t)row * NC + col] = v + aux[col];
        } else if (EPI == 1) {
          float d = aux[row] + aux[col] - 2.0f * v;
          C[(size_t)row * NP + col] = fmaxf(d, 0.0f);
        } else {
          C[(size_t)row * NC + col] = v;
        }
      }
    }
  }
}

// ---------------- unary = -log(softmax(logits)+1e-10), one wave per row ----------
__global__ __launch_bounds__(256) void unary_k(const float* __restrict__ logits,
                                               float* __restrict__ unary) {
  const int wid = threadIdx.x >> 6, lane = threadIdx.x & 63;
  const int row = blockIdx.x * 4 + wid;
  const float* lp = logits + (size_t)row * NC;
  float v[4];
#pragma unroll
  for (int j = 0; j < 4; j++) v[j] = lp[lane + 64 * j];
  float m = fmaxf(fmaxf(v[0], v[1]), fmaxf(v[2], v[3]));
#pragma unroll
  for (int o = 32; o >= 1; o >>= 1) m = fmaxf(m, __shfl_xor(m, o, 64));
  float e[4], s = 0.f;
#pragma unroll
  for (int j = 0; j < 4; j++) { e[j] = expf(v[j] - m); s += e[j]; }
#pragma unroll
  for (int o = 32; o >= 1; o >>= 1) s += __shfl_xor(s, o, 64);
  float* up = unary + (size_t)row * NC;
#pragma unroll
  for (int j = 0; j < 4; j++) up[lane + 64 * j] = -logf(e[j] / s + 1e-10f);
}

// ---------------- per-row 5th-smallest d2 -> atomicAdd(sqrt) into sig ------------
__global__ __launch_bounds__(256) void kth_k(const float* __restrict__ d2,
                                             float* __restrict__ sig) {
  const int row = blockIdx.x, tid = threadIdx.x;
  const float* rp = d2 + (size_t)row * NP;
  float b[5];
#pragma unroll
  for (int q = 0; q < 5; q++) b[q] = __int_as_float(0x7f800000);
  for (int s = 0; s < 16; s++) {
    float v = rp[tid + 256 * s];
    if (v < b[4]) {
      b[4] = v;
#pragma unroll
      for (int q = 4; q > 0; q--)
        if (b[q] < b[q - 1]) { float t = b[q]; b[q] = b[q - 1]; b[q - 1] = t; }
    }
  }
  __shared__ float ls[256 * 5];
#pragma unroll
  for (int q = 0; q < 5; q++) ls[tid * 5 + q] = b[q];
  __syncthreads();
  for (int st = 128; st >= 1; st >>= 1) {
    if (tid < st) {
      float* xs = &ls[tid * 5];
      float* ys = &ls[(tid + st) * 5];
      float r[5]; int i = 0, j = 0;
#pragma unroll
      for (int q = 0; q < 5; q++) r[q] = (xs[i] <= ys[j]) ? xs[i++] : ys[j++];
#pragma unroll
      for (int q = 0; q < 5; q++) xs[q] = r[q];
    }
    __syncthreads();
  }
  if (tid == 0) atomicAdd(sig, sqrtf(ls[4]));
}

// ---------------- Kb = bf16(exp(-d2/(2 sigma^2))) --------------------------------
__global__ __launch_bounds__(256) void expk(const float* __restrict__ d2,
                                            unsigned short* __restrict__ Kb,
                                            const float* __restrict__ sig) {
  float sigma = (*sig) * (1.0f / NP);
  float c = -1.0f / (2.0f * sigma * sigma);
  size_t i = ((size_t)blockIdx.x * 256 + threadIdx.x) * 4;
  float4 v = *(const float4*)&d2[i];
  ushort4 o;
  o.x = f2b(expf(v.x * c)); o.y = f2b(expf(v.y * c));
  o.z = f2b(expf(v.z * c)); o.w = f2b(expf(v.w * c));
  *(ushort4*)&Kb[i] = o;
}

// ---------------- softmax(P - unary) -> out(f32), Yt(bf16, transposed), E, conv ---
// PHASE 0: init (P treated as 0, no E/conv).  PHASE 1: iteration step.
template <int PHASE>
__global__ __launch_bounds__(256) void smax_k(const float* __restrict__ unary,
                                              const float* __restrict__ P,
                                              float* __restrict__ Yout,
                                              unsigned short* __restrict__ Yt,
                                              int iter, int* done, float* oldE,
                                              double* Ed, unsigned* ctr) {
  if (PHASE == 1) { if (*done) return; }
  const int tid = threadIdx.x;
  const int wid = tid >> 6, lane = tid & 63;
  const int rb = blockIdx.x;  // 16 rows per block
  __shared__ __align__(16) unsigned short yt[256][24];  // [col][row] padded
  double epart = 0.0;
  for (int rr = wid; rr < 16; rr += 4) {
    const int row = rb * 16 + rr;
    float u[4], z[4], pv[4];
#pragma unroll
    for (int j = 0; j < 4; j++) {
      int c = lane + 64 * j;
      u[j] = unary[(size_t)row * NC + c];
      pv[j] = PHASE ? P[(size_t)row * NC + c] : 0.0f;
      z[j] = pv[j] - u[j];
    }
    float m = fmaxf(fmaxf(z[0], z[1]), fmaxf(z[2], z[3]));
#pragma unroll
    for (int o = 32; o >= 1; o >>= 1) m = fmaxf(m, __shfl_xor(m, o, 64));
    float e[4], s = 0.f;
#pragma unroll
    for (int j = 0; j < 4; j++) { e[j] = expf(z[j] - m); s += e[j]; }
#pragma unroll
    for (int o = 32; o >= 1; o >>= 1) s += __shfl_xor(s, o, 64);
#pragma unroll
    for (int j = 0; j < 4; j++) {
      int c = lane + 64 * j;
      float y = e[j] / s;
      Yout[(size_t)row * NC + c] = y;
      yt[c][rr] = f2b(y);
      if (PHASE)
        epart += (double)(y * (u[j] - pv[j] + logf(fmaxf(y, 1e-20f))));
    }
  }
  __syncthreads();
  {  // write transposed tile: Yt[c][rb*16 .. +15]
    int c = tid;
    uint4 a = *(const uint4*)&yt[c][0];
    uint4 bq = *(const uint4*)&yt[c][8];
    unsigned short* dst = Yt + (size_t)c * NP + rb * 16;
    *(uint4*)dst = a;
    *(uint4*)(dst + 8) = bq;
  }
  if (PHASE) {
    __shared__ double ered[256];
    ered[tid] = epart; __syncthreads();
    for (int st = 128; st >= 1; st >>= 1) {
      if (tid < st) ered[tid] += ered[tid + st];
      __syncthreads();
    }
    if (tid == 0) {
      atomicAdd(&Ed[iter], ered[0]);
      __threadfence();
      unsigned old = atomicAdd(&ctr[iter], 1u);
      if (old == gridDim.x - 1) {  // last block: convergence test (f32, as reference)
        double Ecur = atomicAdd(&Ed[iter], 0.0);
        float Ef = (float)Ecur;
        float Eo = *oldE;
        if (iter > 1 && fabsf(Ef - Eo) <= 1e-8f * fabsf(Eo)) *done = 1;
        *oldE = Ef;
      }
    }
  }
}

extern "C" void kernel_launch(void* const* d_in, const int* in_sizes, int n_in,
                              void* d_out, int out_size, void* d_ws, size_t ws_size,
                              hipStream_t stream) {
  const float* x = (const float*)d_in[0];
  const float* W = (const float*)d_in[1];
  const float* bias = (const float*)d_in[2];
  float* out = (float*)d_out;

  char* p = (char*)d_ws;
  auto take = [&](size_t bytes) {
    char* r = p;
    p += (bytes + 255) & ~(size_t)255;
    return r;
  };
  float* d2          = (float*)take((size_t)NP * NP * 4);          // 64 MB
  unsigned short* Kb = (unsigned short*)take((size_t)NP * NP * 2); // 32 MB
  unsigned short* F  = (unsigned short*)take((size_t)NP * DIMF * 2);
  unsigned short* xb = (unsigned short*)take((size_t)NP * DIMF * 2);
  unsigned short* Wb = (unsigned short*)take((size_t)NC * DIMF * 2);
  unsigned short* Yt = (unsigned short*)take((size_t)NC * NP * 2);
  float* logits = (float*)take((size_t)NP * NC * 4);
  float* unary  = (float*)take((size_t)NP * NC * 4);
  float* P      = (float*)take((size_t)NP * NC * 4);
  float* sqF    = (float*)take((size_t)NP * 4);
  float* sig    = (float*)take(256);
  int* done     = (int*)take(256);
  float* oldE   = (float*)take(256);
  double* Ed    = (double*)take(MAXIT * 8);
  unsigned* ctr = (unsigned*)take(MAXIT * 4);

  initk<<<1, 128, 0, stream>>>(done, oldE, Ed, ctr, sig);
  castk<<<512, 256, 0, stream>>>(W, Wb);
  rownorm<<<NP, 256, 0, stream>>>(x, F, xb, sqF);
  // logits = x @ W^T + b
  gemm_bt<64, 64, 4, 1, 0><<<dim3(64, 4), 256, 0, stream>>>(xb, Wb, logits, NP, NC, DIMF, bias, done);
  unary_k<<<1024, 256, 0, stream>>>(logits, unary);
  // Y0 = softmax(-unary)
  smax_k<0><<<256, 256, 0, stream>>>(unary, (const float*)nullptr, out, Yt, 0, done, oldE, Ed, ctr);
  // d2 = max(sq_i + sq_j - 2 F F^T, 0)
  gemm_bt<128, 128, 2, 2, 1><<<dim3(32, 32), 256, 0, stream>>>(F, F, d2, NP, NP, DIMF, sqF, done);
  kth_k<<<NP, 256, 0, stream>>>(d2, sig);
  expk<<<16384, 256, 0, stream>>>(d2, Kb, sig);
  // laplacian optimization loop (freeze-on-convergence via done flag)
  for (int i = 0; i < MAXIT; i++) {
    gemm_bt<64, 64, 4, 1, 2><<<dim3(64, 4), 256, 0, stream>>>(Kb, Yt, P, NP, NC, NP, (const float*)nullptr, done);
    smax_k<1><<<256, 256, 0, stream>>>(unary, P, out, Yt, i, done, oldE, Ed, ctr);
  }
}

// Round 4
// 910.222 us; speedup vs baseline: 1.1109x; 1.1109x over previous
//
#include <hip/hip_runtime.h>
#include <hip/hip_cooperative_groups.h>
#include <cstdint>

namespace cg = cooperative_groups;

#define NP 4096   // points
#define DIMF 2048 // feature dim
#define NC 256    // classes
#define MAXIT 100

typedef __bf16 bf16x8 __attribute__((ext_vector_type(8)));
typedef float f32x4 __attribute__((ext_vector_type(4)));

__device__ inline unsigned short f2b(float f) {
  union { float f; unsigned u; } v; v.f = f;
  unsigned r = v.u + 0x7fffu + ((v.u >> 16) & 1u);  // RNE
  return (unsigned short)(r >> 16);
}
__device__ inline float b2f(unsigned short u) {
  union { unsigned u; float f; } v; v.u = ((unsigned)u) << 16;
  return v.f;
}

// ---------------- init ----------------
__global__ __launch_bounds__(128) void initk(double* Ed, float* sig) {
  int t = threadIdx.x;
  if (t < MAXIT) Ed[t] = 0.0;
  if (t == 0) *sig = 0.0f;
}

// ---------------- W f32 -> bf16 ----------------
__global__ __launch_bounds__(256) void castk(const float* __restrict__ W,
                                             unsigned short* __restrict__ Wb) {
  size_t i = ((size_t)blockIdx.x * 256 + threadIdx.x) * 4;
  float4 v = *(const float4*)&W[i];
  ushort4 o; o.x = f2b(v.x); o.y = f2b(v.y); o.z = f2b(v.z); o.w = f2b(v.w);
  *(ushort4*)&Wb[i] = o;
}

// ---------------- row-normalize x -> F(bf16), x -> xb(bf16), sqF ----------------
__global__ __launch_bounds__(256) void rownorm(const float* __restrict__ x,
                                               unsigned short* __restrict__ F,
                                               unsigned short* __restrict__ xb,
                                               float* __restrict__ sqF) {
  const int row = blockIdx.x, tid = threadIdx.x;
  const float* rp = x + (size_t)row * DIMF;
  float4 a = *(const float4*)&rp[tid * 8];
  float4 b = *(const float4*)&rp[tid * 8 + 4];
  float f[8] = {a.x, a.y, a.z, a.w, b.x, b.y, b.z, b.w};
  float s = 0.f;
#pragma unroll
  for (int k = 0; k < 8; k++) s += f[k] * f[k];
  __shared__ float red[256];
  red[tid] = s; __syncthreads();
  for (int st = 128; st >= 1; st >>= 1) {
    if (tid < st) red[tid] += red[tid + st];
    __syncthreads();
  }
  float inv = 1.0f / sqrtf(red[0]);
  __syncthreads();
  unsigned short fb[8], xbv[8];
  float s2 = 0.f;
#pragma unroll
  for (int k = 0; k < 8; k++) {
    fb[k] = f2b(f[k] * inv);
    xbv[k] = f2b(f[k]);
    float q = b2f(fb[k]);
    s2 += q * q;
  }
  *(ushort4*)&F[(size_t)row * DIMF + tid * 8]      = *(ushort4*)&fb[0];
  *(ushort4*)&F[(size_t)row * DIMF + tid * 8 + 4]  = *(ushort4*)&fb[4];
  *(ushort4*)&xb[(size_t)row * DIMF + tid * 8]     = *(ushort4*)&xbv[0];
  *(ushort4*)&xb[(size_t)row * DIMF + tid * 8 + 4] = *(ushort4*)&xbv[4];
  red[tid] = s2; __syncthreads();
  for (int st = 128; st >= 1; st >>= 1) {
    if (tid < st) red[tid] += red[tid + st];
    __syncthreads();
  }
  if (tid == 0) sqF[row] = red[0];
}

// ---------------- r1-validated reg-staged GEMM: C = A[M,K]*B[N,K]^T ----
// EPI 0: C = acc + aux[col]   (logits, aux = bias)
// EPI 1: C = max(aux[row]+aux[col]-2*acc, 0)   (d2, aux = sqF)
template <int BM, int BN, int WR, int WC, int EPI>
__global__ __launch_bounds__(256) void gemm_bt(const unsigned short* __restrict__ A,
                                               const unsigned short* __restrict__ B,
                                               float* __restrict__ C,
                                               int M, int N, int K,
                                               const float* __restrict__ aux) {
  constexpr int WM = BM / WR, WN = BN / WC;
  constexpr int TM = WM / 16, TN = WN / 16;
  constexpr int LDT = 40;  // padded row stride (bf16 elems)
  __shared__ __align__(16) unsigned short sA[BM * LDT];
  __shared__ __align__(16) unsigned short sB[BN * LDT];
  const int tid = threadIdx.x;
  const int wid = tid >> 6, lane = tid & 63;
  const int wr = wid / WC, wc = wid % WC;
  const int l15 = lane & 15, l16 = lane >> 4;
  const int bm = blockIdx.x * BM, bn = blockIdx.y * BN;
  f32x4 acc[TM][TN];
#pragma unroll
  for (int m = 0; m < TM; m++)
#pragma unroll
    for (int n = 0; n < TN; n++) acc[m][n] = 0.0f;

  for (int k0 = 0; k0 < K; k0 += 32) {
    for (int i = tid; i < BM * 4; i += 256) {
      int r = i >> 2, ch = i & 3;
      *(uint4*)&sA[r * LDT + ch * 8] =
          *(const uint4*)&A[(size_t)(bm + r) * K + k0 + ch * 8];
    }
    for (int i = tid; i < BN * 4; i += 256) {
      int r = i >> 2, ch = i & 3;
      *(uint4*)&sB[r * LDT + ch * 8] =
          *(const uint4*)&B[(size_t)(bn + r) * K + k0 + ch * 8];
    }
    __syncthreads();
    bf16x8 af[TM], bf[TN];
#pragma unroll
    for (int m = 0; m < TM; m++)
      af[m] = *(const bf16x8*)&sA[(wr * WM + m * 16 + l15) * LDT + l16 * 8];
#pragma unroll
    for (int n = 0; n < TN; n++)
      bf[n] = *(const bf16x8*)&sB[(wc * WN + n * 16 + l15) * LDT + l16 * 8];
#pragma unroll
    for (int m = 0; m < TM; m++)
#pragma unroll
      for (int n = 0; n < TN; n++)
        acc[m][n] = __builtin_amdgcn_mfma_f32_16x16x32_bf16(af[m], bf[n], acc[m][n], 0, 0, 0);
    __syncthreads();
  }
#pragma unroll
  for (int m = 0; m < TM; m++) {
    int row0 = bm + wr * WM + m * 16 + l16 * 4;
#pragma unroll
    for (int n = 0; n < TN; n++) {
      int col = bn + wc * WN + n * 16 + l15;
#pragma unroll
      for (int j = 0; j < 4; j++) {
        int row = row0 + j;
        float v = acc[m][n][j];
        if (EPI == 0) {
          C[(size_t)row * NC + col] = v + aux[col];
        } else {
          float d = aux[row] + aux[col] - 2.0f * v;
          C[(size_t)row * NP + col] = fmaxf(d, 0.0f);
        }
      }
    }
  }
}

// ---------------- unary = -log(softmax(logits)+1e-10), one wave per row ----------
__global__ __launch_bounds__(256) void unary_k(const float* __restrict__ logits,
                                               float* __restrict__ unary) {
  const int wid = threadIdx.x >> 6, lane = threadIdx.x & 63;
  const int row = blockIdx.x * 4 + wid;
  const float* lp = logits + (size_t)row * NC;
  float v[4];
#pragma unroll
  for (int j = 0; j < 4; j++) v[j] = lp[lane + 64 * j];
  float m = fmaxf(fmaxf(v[0], v[1]), fmaxf(v[2], v[3]));
#pragma unroll
  for (int o = 32; o >= 1; o >>= 1) m = fmaxf(m, __shfl_xor(m, o, 64));
  float e[4], s = 0.f;
#pragma unroll
  for (int j = 0; j < 4; j++) { e[j] = expf(v[j] - m); s += e[j]; }
#pragma unroll
  for (int o = 32; o >= 1; o >>= 1) s += __shfl_xor(s, o, 64);
  float* up = unary + (size_t)row * NC;
#pragma unroll
  for (int j = 0; j < 4; j++) up[lane + 64 * j] = -logf(e[j] / s + 1e-10f);
}

// ---------------- Y0 = softmax(-unary) -> out(f32), Yt(bf16 transposed) ----------
__global__ __launch_bounds__(256) void smax0(const float* __restrict__ unary,
                                             float* __restrict__ Yout,
                                             unsigned short* __restrict__ Yt) {
  const int tid = threadIdx.x;
  const int wid = tid >> 6, lane = tid & 63;
  const int rb = blockIdx.x;  // 16 rows per block
  __shared__ __align__(16) unsigned short yt[256][24];
  for (int rr = wid; rr < 16; rr += 4) {
    const int row = rb * 16 + rr;
    float z[4];
#pragma unroll
    for (int j = 0; j < 4; j++) z[j] = -unary[(size_t)row * NC + lane + 64 * j];
    float m = fmaxf(fmaxf(z[0], z[1]), fmaxf(z[2], z[3]));
#pragma unroll
    for (int o = 32; o >= 1; o >>= 1) m = fmaxf(m, __shfl_xor(m, o, 64));
    float e[4], s = 0.f;
#pragma unroll
    for (int j = 0; j < 4; j++) { e[j] = expf(z[j] - m); s += e[j]; }
#pragma unroll
    for (int o = 32; o >= 1; o >>= 1) s += __shfl_xor(s, o, 64);
#pragma unroll
    for (int j = 0; j < 4; j++) {
      int c = lane + 64 * j;
      float y = e[j] / s;
      Yout[(size_t)row * NC + c] = y;
      yt[c][rr] = f2b(y);
    }
  }
  __syncthreads();
  int c = tid;
  uint4 a = *(const uint4*)&yt[c][0];
  uint4 bq = *(const uint4*)&yt[c][8];
  unsigned short* dst = Yt + (size_t)c * NP + rb * 16;
  *(uint4*)dst = a;
  *(uint4*)(dst + 8) = bq;
}

// ---------------- per-row 5th-smallest d2 -> atomicAdd(sqrt) into sig ------------
__global__ __launch_bounds__(256) void kth_k(const float* __restrict__ d2,
                                             float* __restrict__ sig) {
  const int row = blockIdx.x, tid = threadIdx.x;
  const float* rp = d2 + (size_t)row * NP;
  float b[5];
#pragma unroll
  for (int q = 0; q < 5; q++) b[q] = __int_as_float(0x7f800000);
  for (int s = 0; s < 16; s++) {
    float v = rp[tid + 256 * s];
    if (v < b[4]) {
      b[4] = v;
#pragma unroll
      for (int q = 4; q > 0; q--)
        if (b[q] < b[q - 1]) { float t = b[q]; b[q] = b[q - 1]; b[q - 1] = t; }
    }
  }
  __shared__ float ls[256 * 5];
#pragma unroll
  for (int q = 0; q < 5; q++) ls[tid * 5 + q] = b[q];
  __syncthreads();
  for (int st = 128; st >= 1; st >>= 1) {
    if (tid < st) {
      float* xs = &ls[tid * 5];
      float* ys = &ls[(tid + st) * 5];
      float r[5]; int i = 0, j = 0;
#pragma unroll
      for (int q = 0; q < 5; q++) r[q] = (xs[i] <= ys[j]) ? xs[i++] : ys[j++];
#pragma unroll
      for (int q = 0; q < 5; q++) xs[q] = r[q];
    }
    __syncthreads();
  }
  if (tid == 0) atomicAdd(sig, sqrtf(ls[4]));
}

// ---------------- Kb = bf16(exp(-d2/(2 sigma^2))) --------------------------------
__global__ __launch_bounds__(256) void expk(const float* __restrict__ d2,
                                            unsigned short* __restrict__ Kb,
                                            const float* __restrict__ sig) {
  float sigma = (*sig) * (1.0f / NP);
  float c = -1.0f / (2.0f * sigma * sigma);
  size_t i = ((size_t)blockIdx.x * 256 + threadIdx.x) * 4;
  float4 v = *(const float4*)&d2[i];
  ushort4 o;
  o.x = f2b(expf(v.x * c)); o.y = f2b(expf(v.y * c));
  o.z = f2b(expf(v.z * c)); o.w = f2b(expf(v.w * c));
  *(ushort4*)&Kb[i] = o;
}

// ---------------- persistent cooperative loop kernel -----------------------------
// 256 blocks x 512 threads (8 waves).  block = (rb, ks): rb in [0,64) rows 64,
// ks in [0,4) k-slice of 1024.  Per iter:
//   phase A: partial[ks] = Kb[rb-rows][kslice] @ Yt[:, kslice]^T  (reg-staged LDS)
//   grid.sync
//   phase B: rows blk*16..+15: P = sum_s partial; softmax(P - unary);
//            out(f32), Yt(bf16 transposed), E -> atomicAdd Ed[iter]
//   grid.sync; uniform convergence check -> break.
__global__ __launch_bounds__(512, 4) void loop_k(const unsigned short* __restrict__ Kb,
                                                 unsigned short* __restrict__ Yt,
                                                 const float* __restrict__ unary,
                                                 float* __restrict__ out,
                                                 float* __restrict__ partial,
                                                 double* __restrict__ Ed) {
  const int tid = threadIdx.x, lane = tid & 63, wid = tid >> 6;
  const int blk = blockIdx.x;
  const int rb = blk >> 2, ks = blk & 3;   // 64-row block, 1024-wide k-slice
  const int wr = wid >> 2, wc = wid & 3;   // 2x4 wave grid, wave tile 32x64
  const int l15 = lane & 15, l16 = lane >> 4;
  constexpr int LDT = 72;                  // padded (144B row stride: 2-way-free)
  __shared__ __align__(16) unsigned short sA[64 * LDT];    //  9.2 KB
  __shared__ __align__(16) unsigned short sB[256 * LDT];   // 36.9 KB
  __shared__ __align__(16) unsigned short yt[256 * 24];    // 12.3 KB
  __shared__ double ered[8];
  float oldEf = __int_as_float(0x7f800000);

  for (int iter = 0; iter < MAXIT; ++iter) {
    // ---------------- phase A: partial GEMM (reg-staged, r1-validated pattern) ----
    f32x4 acc[2][4];
#pragma unroll
    for (int m = 0; m < 2; m++)
#pragma unroll
      for (int n = 0; n < 4; n++) acc[m][n] = 0.0f;

    for (int kb = 0; kb < 16; ++kb) {
      const int kofs = ks * 1024 + kb * 64;
      {
        int u = tid, r = u >> 3, c = u & 7;
        *(uint4*)&sA[r * LDT + c * 8] =
            *(const uint4*)&Kb[(size_t)(rb * 64 + r) * NP + kofs + c * 8];
      }
#pragma unroll
      for (int j = 0; j < 4; ++j) {
        int u = j * 512 + tid, r = u >> 3, c = u & 7;
        *(uint4*)&sB[r * LDT + c * 8] =
            *(const uint4*)&Yt[(size_t)r * NP + kofs + c * 8];
      }
      __syncthreads();
#pragma unroll
      for (int kk = 0; kk < 2; ++kk) {
        bf16x8 af[2], bf[4];
#pragma unroll
        for (int m = 0; m < 2; ++m)
          af[m] = *(const bf16x8*)&sA[(wr * 32 + m * 16 + l15) * LDT + (kk * 4 + l16) * 8];
#pragma unroll
        for (int n = 0; n < 4; ++n)
          bf[n] = *(const bf16x8*)&sB[(wc * 64 + n * 16 + l15) * LDT + (kk * 4 + l16) * 8];
#pragma unroll
        for (int m = 0; m < 2; ++m)
#pragma unroll
          for (int n = 0; n < 4; ++n)
            acc[m][n] = __builtin_amdgcn_mfma_f32_16x16x32_bf16(af[m], bf[n], acc[m][n], 0, 0, 0);
      }
      __syncthreads();
    }
    {
      float* pp = partial + (size_t)ks * ((size_t)NP * NC);
#pragma unroll
      for (int m = 0; m < 2; ++m) {
        int row0 = rb * 64 + wr * 32 + m * 16 + l16 * 4;
#pragma unroll
        for (int n = 0; n < 4; ++n) {
          int col = wc * 64 + n * 16 + l15;
#pragma unroll
          for (int j = 0; j < 4; ++j)
            pp[(size_t)(row0 + j) * NC + col] = acc[m][n][j];
        }
      }
    }
    cg::this_grid().sync();

    // ---------------- phase B: reduce + softmax + E (16 rows per block) ----------
    double ep = 0.0;
#pragma unroll
    for (int h = 0; h < 2; ++h) {
      const int rr = wid * 2 + h;
      const int row = blk * 16 + rr;
      const int c0 = lane * 4;
      float pv[4] = {0.f, 0.f, 0.f, 0.f};
#pragma unroll
      for (int s = 0; s < 4; ++s) {
        float4 t4 = *(const float4*)&partial[(size_t)s * ((size_t)NP * NC) +
                                             (size_t)row * NC + c0];
        pv[0] += t4.x; pv[1] += t4.y; pv[2] += t4.z; pv[3] += t4.w;
      }
      float4 u4 = *(const float4*)&unary[(size_t)row * NC + c0];
      float uu[4] = {u4.x, u4.y, u4.z, u4.w};
      float z[4];
#pragma unroll
      for (int q = 0; q < 4; ++q) z[q] = pv[q] - uu[q];
      float m = fmaxf(fmaxf(z[0], z[1]), fmaxf(z[2], z[3]));
#pragma unroll
      for (int o = 32; o >= 1; o >>= 1) m = fmaxf(m, __shfl_xor(m, o, 64));
      float e[4], ssum = 0.f;
#pragma unroll
      for (int q = 0; q < 4; ++q) { e[q] = expf(z[q] - m); ssum += e[q]; }
#pragma unroll
      for (int o = 32; o >= 1; o >>= 1) ssum += __shfl_xor(ssum, o, 64);
      float inv = 1.0f / ssum;
      float4 o4;
      float y[4];
#pragma unroll
      for (int q = 0; q < 4; ++q) {
        y[q] = e[q] * inv;
        ep += (double)(y[q] * (uu[q] - pv[q] + logf(fmaxf(y[q], 1e-20f))));
        yt[(c0 + q) * 24 + rr] = f2b(y[q]);
      }
      o4.x = y[0]; o4.y = y[1]; o4.z = y[2]; o4.w = y[3];
      *(float4*)&out[(size_t)row * NC + c0] = o4;
    }
#pragma unroll
    for (int o = 32; o >= 1; o >>= 1) ep += __shfl_xor(ep, o, 64);
    if (lane == 0) ered[wid] = ep;
    __syncthreads();
    if (tid < 256) {  // pack 16 transposed rows for class c=tid
      uint4 a = *(const uint4*)&yt[tid * 24];
      uint4 bq = *(const uint4*)&yt[tid * 24 + 8];
      unsigned short* dst = Yt + (size_t)tid * NP + (size_t)blk * 16;
      *(uint4*)dst = a;
      *(uint4*)(dst + 8) = bq;
    }
    if (tid == 0) {
      double eblk = 0.0;
#pragma unroll
      for (int w = 0; w < 8; ++w) eblk += ered[w];
      atomicAdd(&Ed[iter], eblk);
    }
    cg::this_grid().sync();

    double Ec = __hip_atomic_load(&Ed[iter], __ATOMIC_RELAXED, __HIP_MEMORY_SCOPE_AGENT);
    float Ef = (float)Ec;
    if (iter > 1 && fabsf(Ef - oldEf) <= 1e-8f * fabsf(oldEf)) break;  // frozen
    oldEf = Ef;
  }
}

extern "C" void kernel_launch(void* const* d_in, const int* in_sizes, int n_in,
                              void* d_out, int out_size, void* d_ws, size_t ws_size,
                              hipStream_t stream) {
  const float* x = (const float*)d_in[0];
  const float* W = (const float*)d_in[1];
  const float* bias = (const float*)d_in[2];
  float* out = (float*)d_out;

  char* p = (char*)d_ws;
  auto take = [&](size_t bytes) {
    char* r = p;
    p += (bytes + 255) & ~(size_t)255;
    return r;
  };
  float* d2          = (float*)take((size_t)NP * NP * 4);          // 64 MB (reused as partials)
  unsigned short* Kb = (unsigned short*)take((size_t)NP * NP * 2); // 32 MB
  unsigned short* F  = (unsigned short*)take((size_t)NP * DIMF * 2);
  unsigned short* xb = (unsigned short*)take((size_t)NP * DIMF * 2);
  unsigned short* Wb = (unsigned short*)take((size_t)NC * DIMF * 2);
  unsigned short* Yt = (unsigned short*)take((size_t)NC * NP * 2);
  float* logits = (float*)take((size_t)NP * NC * 4);
  float* unary  = (float*)take((size_t)NP * NC * 4);
  float* sqF    = (float*)take((size_t)NP * 4);
  float* sig    = (float*)take(256);
  double* Ed    = (double*)take(MAXIT * 8);
  float* partial = d2;  // d2 dead after expk; 16 MB of partials fit in its 64 MB

  initk<<<1, 128, 0, stream>>>(Ed, sig);
  castk<<<512, 256, 0, stream>>>(W, Wb);
  rownorm<<<NP, 256, 0, stream>>>(x, F, xb, sqF);
  // logits = x @ W^T + b
  gemm_bt<64, 64, 4, 1, 0><<<dim3(64, 4), 256, 0, stream>>>(xb, Wb, logits, NP, NC, DIMF, bias);
  unary_k<<<1024, 256, 0, stream>>>(logits, unary);
  smax0<<<256, 256, 0, stream>>>(unary, out, Yt);
  // d2 = max(sq_i + sq_j - 2 F F^T, 0)
  gemm_bt<128, 128, 2, 2, 1><<<dim3(32, 32), 256, 0, stream>>>(F, F, d2, NP, NP, DIMF, sqF);
  kth_k<<<NP, 256, 0, stream>>>(d2, sig);
  expk<<<16384, 256, 0, stream>>>(d2, Kb, sig);
  // whole laplacian-optimization loop in one persistent cooperative kernel
  {
    const unsigned short* Kb_a = Kb;
    unsigned short* Yt_a = Yt;
    const float* un_a = unary;
    float* out_a = out;
    float* pa_a = partial;
    double* Ed_a = Ed;
    void* args[] = {(void*)&Kb_a, (void*)&Yt_a, (void*)&un_a,
                    (void*)&out_a, (void*)&pa_a, (void*)&Ed_a};
    hipLaunchCooperativeKernel((const void*)loop_k, dim3(256), dim3(512),
                               args, 0, stream);
  }
}